// Round 11
// baseline (294.784 us; speedup 1.0000x reference)
//
#include <hip/hip_runtime.h>

#define C_CH 173
#define L_IN 400
#define EPSV 1e-5f
#define KFEAT 55360  // C*32*10

typedef __fp16   fp16x2 __attribute__((ext_vector_type(2)));
typedef _Float16 f16x8  __attribute__((ext_vector_type(8)));
typedef float    f32x4  __attribute__((ext_vector_type(4)));
typedef float    f32x16 __attribute__((ext_vector_type(16)));

#define Y1T_STRIDE 36   // f16/row = 18 dwords: even (8B-aligned b64), 2-way = free
#define Y1T_ROWS   406  // row r = y1 time t+3; rows 0..2, 403..405 zeroed halo

#define N1 (173 * 3584)  // w2T elems
#define N2 (173 * 512)   // w1T elems
#define N3 (173 * 96)    // BN consts per c: s1[16] sh1[16] s2[32] sh2[32]

// 8-lane max via DPP (pure VALU, no DS pipe)
template <int CTRL>
__device__ __forceinline__ float dppf(float v) {
    int s = __builtin_bit_cast(int, v);
    int r = __builtin_amdgcn_update_dpp(0, s, CTRL, 0xF, 0xF, true);
    return __builtin_bit_cast(float, r);
}

// ---------------------------------------------------------------------------
// Prep kernel: materialize per-channel weight layouts + BN consts once/call.
//  w2T_g[c][dt*512 + f*16 + g] f16 ; w1T_g[c][g*32+k] f16 (k>=9 zero)
//  sc_g[c*96 + r]: r<16 scale1 | r<32 shift1 | r<64 scale2 | r<96 shift2
// ---------------------------------------------------------------------------
__global__ __launch_bounds__(256) void prep_kernel(
    const float* __restrict__ w1, const float* __restrict__ b1,
    const float* __restrict__ g1, const float* __restrict__ beta1,
    const float* __restrict__ m1, const float* __restrict__ v1,
    const float* __restrict__ w2, const float* __restrict__ b2,
    const float* __restrict__ g2, const float* __restrict__ beta2,
    const float* __restrict__ m2, const float* __restrict__ v2,
    _Float16* __restrict__ w2T_g, _Float16* __restrict__ w1T_g,
    float* __restrict__ sc_g)
{
    const int idx = blockIdx.x * 256 + threadIdx.x;
    if (idx < N1) {
        int c = idx / 3584, r = idx - c * 3584;
        int dt = r >> 9, fg = r & 511;
        int f = fg >> 4, g = fg & 15;
        w2T_g[idx] = (_Float16)w2[c * 3584 + f * 112 + g * 7 + dt];
    } else if (idx < N1 + N2) {
        int j = idx - N1;
        int c = j / 512, r = j - c * 512;
        int g = r >> 5, k = r & 31;
        w1T_g[j] = (k < 9) ? (_Float16)w1[c * 144 + g * 9 + k] : (_Float16)0.0f;
    } else if (idx < N1 + N2 + N3) {
        int j = idx - N1 - N2;
        int c = j / 96, r = j - c * 96;
        float o;
        if (r < 32) {
            int g  = r & 15;
            int cf = c * 16 + g;
            float inv = g1[cf] * rsqrtf(v1[cf] + EPSV);
            o = (r < 16) ? inv : (b1[cf] - m1[cf]) * inv + beta1[cf];
        } else {
            int f  = (r - 32) & 31;
            int cf = c * 32 + f;
            float inv = g2[cf] * rsqrtf(v2[cf] + EPSV);
            o = (r < 64) ? inv : (b2[cf] - m2[cf]) * inv + beta2[cf];
        }
        sc_g[j] = o;
    }
}

// ---------------------------------------------------------------------------
// Tower kernel: one block per (c, batch-group of 8). 320 threads = 5 waves.
// Software-pipelined batch loop (R10 was 3 barriers/batch, phases fully
// serialized; no pipe >40% busy -> barrier/latency-bound):
//   iter nb:  [conv1(nb) || pool(nb-1)]   (y1T writes vs segmax reads)
//             sync
//             [conv2(nb) || stage_x(nb+1)] (x untouched by conv2: HBM
//                                           latency hides under MFMA/DS)
//             sync
// = 2 barriers/batch, x-load latency fully hidden, weight staging 1x/8.
// LDS 43008 B (3 blocks/CU). VGPR pinned <=64 via __launch_bounds__(320,8).
// ---------------------------------------------------------------------------
__global__ __launch_bounds__(320, 8) void tower_kernel(
    const float* __restrict__ x,
    const _Float16* __restrict__ w2T_g, const _Float16* __restrict__ w1T_g,
    const float* __restrict__ sc_g,
    _Float16* __restrict__ featH)
{
    __shared__ __align__(16) _Float16 xa_s[432];             // xa[i] = x_s[i]
    __shared__ __align__(16) _Float16 xb_s[432];             // xb[i] = x_s[i+1]
    __shared__ __align__(16) _Float16 w1T_s[16 * 32];        // [g][k]
    __shared__ __align__(16) _Float16 y1T_s[Y1T_ROWS * Y1T_STRIDE];
    __shared__ __align__(16) _Float16 w2T_s[7 * 512];        // [dt][f][g]
    __shared__ _Float16               segmax_s[32 * 50];     // [f][seg] f16
    __shared__ __align__(16) float    cst_s[96];  // s1[16] sh1[16] s2[32] sh2[32]

    const int c   = blockIdx.x;
    const int tid = threadIdx.x;

    // ---- once-per-block staging (coalesced) + prestage x(0) ----
    {
        const int4* w2src = (const int4*)(w2T_g + (size_t)c * 3584);
        for (int i = tid; i < 448; i += 320) ((int4*)w2T_s)[i] = w2src[i];
        const int4* w1src = (const int4*)(w1T_g + c * 512);
        if (tid < 64) ((int4*)w1T_s)[tid] = w1src[tid];
        const float4* csrc = (const float4*)(sc_g + c * 96);
        if (tid >= 64 && tid < 88) ((float4*)cst_s)[tid - 64] = csrc[tid - 64];
        // zero y1T halo rows 0..2 and 403..405 (6 rows x 18 dwords)
        if (tid >= 88 && tid < 196) {
            int i = tid - 88;
            int r = i / 18, cx = i - r * 18;
            int row = (r < 3) ? r : (400 + r);
            ((int*)y1T_s)[row * 18 + cx] = 0;
        }
        // prestage x for batch 0
        const int b0 = blockIdx.y * 8;
        const float* xrow = x + ((size_t)b0 * C_CH + c) * L_IN;
        for (int i = tid; i < 432; i += 320) {
            float v = (i >= 4 && i < 404) ? xrow[i - 4] : 0.0f;
            _Float16 h = (_Float16)v;
            xa_s[i] = h;
            if (i > 0) xb_s[i - 1] = h;
        }
        if (tid == 0) xb_s[431] = (_Float16)0.0f;
    }
    __syncthreads();

    for (int nb = 0; nb < 8; ++nb) {
        const int b = blockIdx.y * 8 + nb;

        // ---- phase A: conv1(nb) || pool(nb-1) ----
        // conv1 via mfma_16x16x32_f16: A[m=g][k]=w1T, B[k][n]=x[t0+n+k-4];
        // lane n=lane&15, k-group q=lane>>4; parity of n selects xa/xb copy
        // so the lane's 8-f16 window is dword-aligned.
        {
            const int lane = tid & 63;
            const int wv5  = tid >> 6;
            const int nl   = lane & 15;
            const int q    = lane >> 4;
            union { int4 v; f16x8 h; } a1;
            a1.v = *(const int4*)((const int*)w1T_s + nl * 16 + q * 4);
            float s1r[4], sh1r[4];
#pragma unroll
            for (int r = 0; r < 4; ++r) {
                s1r[r]  = cst_s[q * 4 + r];
                sh1r[r] = cst_s[16 + q * 4 + r];
            }
            const int* xsel = (const int*)((nl & 1) ? xb_s : xa_s);
            for (int tile = 0; tile < 5; ++tile) {
                const int t0 = (wv5 * 5 + tile) * 16;
                const int dw = (t0 + nl + q * 8) >> 1;
                union { int4 v; f16x8 h; } bf;
                bf.v.x = xsel[dw];
                bf.v.y = xsel[dw + 1];
                bf.v.z = xsel[dw + 2];
                bf.v.w = xsel[dw + 3];
                f32x4 acc = {0.0f, 0.0f, 0.0f, 0.0f};
                acc = __builtin_amdgcn_mfma_f32_16x16x32_f16(a1.h, bf.h, acc, 0, 0, 0);
                union { _Float16 h[4]; int2 d; } pk;
#pragma unroll
                for (int r = 0; r < 4; ++r) {
                    float v = acc[r] * s1r[r] + sh1r[r];
                    pk.h[r] = (_Float16)(v > 0.0f ? v : 0.0f);
                }
                *(int2*)((int*)y1T_s + (t0 + nl + 3) * 18 + q * 2) = pk.d;
            }
        }
        if (nb > 0) {   // pool(nb-1): segmax written before last sync
            const int f = tid & 31;
            const int p = tid >> 5;
            float m = 0.0f;
#pragma unroll
            for (int k = 0; k < 5; ++k)
                m = fmaxf(m, (float)segmax_s[f * 50 + p * 5 + k]);
            featH[(size_t)(b - 1) * KFEAT + (c * 32 + f) * 10 + p] = (_Float16)m;
        }
        __syncthreads();

        // ---- phase B: conv2(nb) || stage_x(nb+1) ----
        if (nb < 7) {   // stage next x; conv2 never touches xa/xb
            const float* xrow = x + ((size_t)(b + 1) * C_CH + c) * L_IN;
            for (int i = tid; i < 432; i += 320) {
                float v = (i >= 4 && i < 404) ? xrow[i - 4] : 0.0f;
                _Float16 h = (_Float16)v;
                xa_s[i] = h;
                if (i > 0) xb_s[i - 1] = h;
            }
            if (tid == 0) xb_s[431] = (_Float16)0.0f;
        }
        {
            const int wv    = tid >> 6;
            const int lane  = tid & 63;
            const int nlane = lane & 31;
            const int half  = lane >> 5;

            union F8q { int4 q; f16x8 h; } af[7];
#pragma unroll
            for (int dt = 0; dt < 7; ++dt)
                af[dt].q = *(const int4*)((const int*)w2T_s + dt * 256 + nlane * 8 + half * 4);

            for (int tile = wv; tile < 13; tile += 5) {
                const int t0  = tile * 32 + nlane;
                const int t0r = t0 < 400 ? t0 : 399;   // rows > 405 don't exist
                f32x16 acc;
#pragma unroll
                for (int i = 0; i < 16; ++i) acc[i] = 0.0f;

#pragma unroll
                for (int dt = 0; dt < 7; ++dt) {
                    const int* p = (const int*)y1T_s + (t0r + dt) * 18 + half * 4;
                    union { int2 d[2]; f16x8 h; } bf;
                    bf.d[0] = *(const int2*)p;
                    bf.d[1] = *(const int2*)(p + 2);
                    acc = __builtin_amdgcn_mfma_f32_32x32x16_f16(af[dt].h, bf.h, acc, 0, 0, 0);
                }

                const bool wr  = ((nlane & 7) == 0) && (t0 < 400);
                const int  seg = t0 >> 3;
#pragma unroll
                for (int reg = 0; reg < 16; ++reg) {
                    int f = (reg & 3) + 8 * (reg >> 2) + 4 * half;
                    float v = acc[reg] * cst_s[32 + f] + cst_s[64 + f];
                    v = fmaxf(v, 0.0f);
                    v = fmaxf(v, dppf<0xB1>(v));    // xor 1
                    v = fmaxf(v, dppf<0x4E>(v));    // xor 2
                    v = fmaxf(v, dppf<0x141>(v));   // row_half_mirror
                    if (wr) segmax_s[f * 50 + seg] = (_Float16)v;
                }
            }
        }
        __syncthreads();
    }

    // ---- epilogue: pool(7) ----
    {
        const int f = tid & 31;
        const int p = tid >> 5;
        float m = 0.0f;
#pragma unroll
        for (int k = 0; k < 5; ++k)
            m = fmaxf(m, (float)segmax_s[f * 50 + p * 5 + k]);
        featH[(size_t)(blockIdx.y * 8 + 7) * KFEAT + (c * 32 + f) * 10 + p] = (_Float16)m;
    }
}

// ---------------------------------------------------------------------------
// FC1 f16 MFMA GEMM, split-K without atomics: 173 blocks x KC=320 (20 steps).
// Each block writes a disjoint partial tile part[kb][128][64].
// ---------------------------------------------------------------------------
__global__ __launch_bounds__(256) void fc1_kernel(
    const _Float16* __restrict__ featH, const float* __restrict__ wc1,
    float* __restrict__ part)
{
    const int tid   = threadIdx.x;
    const int kb    = blockIdx.x;
    const int k0    = kb * 320;
    const int lane  = tid & 63;
    const int wv    = tid >> 6;
    const int nlane = lane & 31;
    const int half  = lane >> 5;
    const int jrow  = wv * 32 + nlane;

    const float*    ap  = wc1   + (size_t)jrow * KFEAT + k0 + half * 8;
    const _Float16* b0p = featH + (size_t)nlane * KFEAT + k0 + half * 8;
    const _Float16* b1p = featH + (size_t)(nlane + 32) * KFEAT + k0 + half * 8;

    f32x16 acc0, acc1;
#pragma unroll
    for (int i = 0; i < 16; ++i) { acc0[i] = 0.0f; acc1[i] = 0.0f; }

#pragma unroll 2
    for (int s = 0; s < 20; ++s) {
        const float4 aw0 = *(const float4*)(ap + s * 16);
        const float4 aw1 = *(const float4*)(ap + s * 16 + 4);
        union { fp16x2 v2[4]; f16x8 h; } a;
        a.v2[0] = __builtin_amdgcn_cvt_pkrtz(aw0.x, aw0.y);
        a.v2[1] = __builtin_amdgcn_cvt_pkrtz(aw0.z, aw0.w);
        a.v2[2] = __builtin_amdgcn_cvt_pkrtz(aw1.x, aw1.y);
        a.v2[3] = __builtin_amdgcn_cvt_pkrtz(aw1.z, aw1.w);

        union { int4 q; f16x8 h; } b0, b1;
        b0.q = *(const int4*)(b0p + s * 16);
        b1.q = *(const int4*)(b1p + s * 16);

        acc0 = __builtin_amdgcn_mfma_f32_32x32x16_f16(a.h, b0.h, acc0, 0, 0, 0);
        acc1 = __builtin_amdgcn_mfma_f32_32x32x16_f16(a.h, b1.h, acc1, 0, 0, 0);
    }

    float* pt = part + (size_t)kb * 8192;
#pragma unroll
    for (int reg = 0; reg < 16; ++reg) {
        int j = wv * 32 + (reg & 3) + 8 * (reg >> 2) + 4 * half;
        pt[j * 64 + nlane]      = acc0[reg];
        pt[j * 64 + 32 + nlane] = acc1[reg];
    }
}

// ---------------------------------------------------------------------------
// Reduce partials: h[idx] = sum_kb part[kb][idx]. Coalesced.
// ---------------------------------------------------------------------------
__global__ __launch_bounds__(256) void reduce_kernel(
    const float* __restrict__ part, float* __restrict__ h_ws)
{
    const int idx = blockIdx.x * 256 + threadIdx.x;   // 0..8191
    float s = 0.0f;
    for (int kb = 0; kb < 173; ++kb)
        s += part[(size_t)kb * 8192 + idx];
    h_ws[idx] = s;
}

// ---------------------------------------------------------------------------
// FC2: out[b] = bc2 + sum_j wc2[j] * relu(h[j][b] + bc1[j])
// ---------------------------------------------------------------------------
__global__ __launch_bounds__(64) void fc2_kernel(
    const float* __restrict__ h_ws, const float* __restrict__ bc1,
    const float* __restrict__ wc2, const float* __restrict__ bc2,
    float* __restrict__ out)
{
    const int b = threadIdx.x;
    float acc = bc2[0];
    for (int j = 0; j < 128; ++j) {
        float hv = h_ws[j * 64 + b] + bc1[j];
        hv = hv > 0.0f ? hv : 0.0f;
        acc += wc2[j] * hv;
    }
    out[b] = acc;
}

extern "C" void kernel_launch(void* const* d_in, const int* in_sizes, int n_in,
                              void* d_out, int out_size, void* d_ws, size_t ws_size,
                              hipStream_t stream)
{
    const float* x     = (const float*)d_in[0];
    const float* w1    = (const float*)d_in[1];
    const float* b1    = (const float*)d_in[2];
    const float* g1    = (const float*)d_in[3];
    const float* beta1 = (const float*)d_in[4];
    const float* m1    = (const float*)d_in[5];
    const float* v1    = (const float*)d_in[6];
    const float* w2    = (const float*)d_in[7];
    const float* b2    = (const float*)d_in[8];
    const float* g2    = (const float*)d_in[9];
    const float* beta2 = (const float*)d_in[10];
    const float* m2    = (const float*)d_in[11];
    const float* v2    = (const float*)d_in[12];
    const float* wc1   = (const float*)d_in[13];
    const float* bc1   = (const float*)d_in[14];
    const float* wc2   = (const float*)d_in[15];
    const float* bc2   = (const float*)d_in[16];

    char* ws = (char*)d_ws;
    _Float16* featH = (_Float16*)ws;                          // 7,086,080 B
    float*    part  = (float*)(ws + 7086080);                 // 5,668,864 B
    float*    h_ws  = (float*)(ws + 12754944);                // 32,768 B
    _Float16* w2T_g = (_Float16*)(ws + 12787712);             // 1,240,064 B
    _Float16* w1T_g = (_Float16*)(ws + 14027776);             // 177,152 B
    float*    sc_g  = (float*)(ws + 14204928);                // 66,432 B

    hipLaunchKernelGGL(prep_kernel, dim3(2834), dim3(256), 0, stream,
                       w1, b1, g1, beta1, m1, v1,
                       w2, b2, g2, beta2, m2, v2, w2T_g, w1T_g, sc_g);

    hipLaunchKernelGGL(tower_kernel, dim3(C_CH, 8), dim3(320), 0, stream,
                       x, w2T_g, w1T_g, sc_g, featH);

    hipLaunchKernelGGL(fc1_kernel, dim3(173), dim3(256), 0, stream,
                       featH, wc1, part);

    hipLaunchKernelGGL(reduce_kernel, dim3(32), dim3(256), 0, stream,
                       part, h_ws);

    hipLaunchKernelGGL(fc2_kernel, dim3(1), dim3(64), 0, stream,
                       h_ws, bc1, wc2, bc2, (float*)d_out);
}